// Round 1
// baseline (463.979 us; speedup 1.0000x reference)
//
#include <hip/hip_runtime.h>

// FFN: out = x + fc2(relu(fc1(LN(x))))
// x: (B*T, 16) fp32, w1: (64,16), b1: (64), w2: (16,64), b2: (16)
// One thread per token; weights broadcast from LDS; fully unrolled fp32 FMA.

constexpr int H = 16;
constexpr int D = 64;

__global__ __launch_bounds__(256, 2) void ffn_kernel(
    const float* __restrict__ x,
    const float* __restrict__ ln_g,
    const float* __restrict__ ln_b,
    const float* __restrict__ w1,
    const float* __restrict__ b1,
    const float* __restrict__ w2,
    const float* __restrict__ b2,
    float* __restrict__ out,
    int ntok)
{
    __shared__ float s_w1[D * H];   // [d][k], rows 64B-aligned -> ds_read_b128
    __shared__ float s_w2[H * D];   // [c][d]
    __shared__ float s_b1[D];
    __shared__ float s_b2[H];
    __shared__ float s_g[H];
    __shared__ float s_be[H];

    const int tid = threadIdx.x;
    for (int i = tid; i < D * H; i += 256) s_w1[i] = w1[i];
    for (int i = tid; i < H * D; i += 256) s_w2[i] = w2[i];
    if (tid < D) s_b1[tid] = b1[tid];
    if (tid < H) { s_b2[tid] = b2[tid]; s_g[tid] = ln_g[tid]; s_be[tid] = ln_b[tid]; }
    __syncthreads();

    const int nthreads = gridDim.x * blockDim.x;
    for (int t = blockIdx.x * blockDim.x + tid; t < ntok; t += nthreads) {
        const float4* xp = (const float4*)(x + (size_t)t * H);
        float4 v0 = xp[0], v1 = xp[1], v2 = xp[2], v3 = xp[3];
        float xs[H] = {v0.x, v0.y, v0.z, v0.w, v1.x, v1.y, v1.z, v1.w,
                       v2.x, v2.y, v2.z, v2.w, v3.x, v3.y, v3.z, v3.w};

        // LayerNorm (fp32, matches np ref closely)
        float sum = 0.f;
        #pragma unroll
        for (int k = 0; k < H; k++) sum += xs[k];
        const float mean = sum * (1.0f / H);
        float vs = 0.f;
        #pragma unroll
        for (int k = 0; k < H; k++) { float d = xs[k] - mean; vs = fmaf(d, d, vs); }
        const float inv = rsqrtf(vs * (1.0f / H) + 1e-5f);

        float y[H];
        #pragma unroll
        for (int k = 0; k < H; k++)
            y[k] = fmaf((xs[k] - mean) * inv, s_g[k], s_be[k]);

        // fc1 + ReLU: h[d] = relu(b1[d] + sum_k y[k]*w1[d,k])
        float h[D];
        #pragma unroll
        for (int d = 0; d < D; d++) {
            float acc = s_b1[d];
            #pragma unroll
            for (int k = 0; k < H; k++) acc = fmaf(y[k], s_w1[d * H + k], acc);
            h[d] = fmaxf(acc, 0.f);
        }

        // fc2 + residual: out[c] = x[c] + b2[c] + sum_d h[d]*w2[c,d]
        float4* op = (float4*)(out + (size_t)t * H);
        #pragma unroll
        for (int c = 0; c < H; c += 4) {
            float o[4];
            #pragma unroll
            for (int j = 0; j < 4; j++) {
                float acc = s_b2[c + j];
                #pragma unroll
                for (int d = 0; d < D; d++) acc = fmaf(h[d], s_w2[(c + j) * D + d], acc);
                o[j] = acc + xs[c + j];
            }
            op[c / 4] = make_float4(o[0], o[1], o[2], o[3]);
        }
    }
}

extern "C" void kernel_launch(void* const* d_in, const int* in_sizes, int n_in,
                              void* d_out, int out_size, void* d_ws, size_t ws_size,
                              hipStream_t stream) {
    const float* x   = (const float*)d_in[0];
    const float* g   = (const float*)d_in[1];
    const float* be  = (const float*)d_in[2];
    const float* w1  = (const float*)d_in[3];
    const float* b1  = (const float*)d_in[4];
    const float* w2  = (const float*)d_in[5];
    const float* b2  = (const float*)d_in[6];
    float* out = (float*)d_out;
    const int ntok = in_sizes[0] / H;

    const int block = 256;
    int grid = (ntok + block * 2 - 1) / (block * 2);   // 2 tokens per thread
    if (grid < 1) grid = 1;
    ffn_kernel<<<grid, block, 0, stream>>>(x, g, be, w1, b1, w2, b2, out, ntok);
}

// Round 2
// 199.151 us; speedup vs baseline: 2.3298x; 2.3298x over previous
//
#include <hip/hip_runtime.h>

// FFN: out = x + fc2(relu(fc1(LN(x)))), x:(ntok,16) fp32
// R2: LDS-staged coalesced I/O (R1 had 8x HBM over-fetch from 64B-stride lane
// access), fused fc1->relu->fc2 inner loop (no h[64] array -> low VGPR),
// padded LDS rows (ROW=20 words: ds_read_b128 stride-20 covers all 32 banks
// per 8 lanes -> conflict-free, and 80B keeps 16B alignment).

constexpr int H = 16;
constexpr int D = 64;
constexpr int BT = 256;    // tokens per block tile
constexpr int ROW = 20;    // padded words per token in LDS

__global__ __launch_bounds__(256, 4) void ffn_kernel(
    const float* __restrict__ x,
    const float* __restrict__ ln_g,
    const float* __restrict__ ln_b,
    const float* __restrict__ w1,
    const float* __restrict__ b1,
    const float* __restrict__ w2,
    const float* __restrict__ b2,
    float* __restrict__ out,
    int ntok)
{
    __shared__ float s_x[BT * ROW];      // 20 KB token tile (in, then out)
    __shared__ float s_w1[D * H];        // [d][k] rows contiguous
    __shared__ float s_w2t[D * H];       // transposed: [d][c] rows contiguous
    __shared__ float s_b1[D];
    __shared__ float s_b2[H], s_g[H], s_be[H];

    const int tid = threadIdx.x;

    // ---- one-time weight staging ----
    for (int i = tid; i < D * H; i += 256) s_w1[i] = w1[i];
    for (int i = tid; i < D * H; i += 256) {
        int c = i >> 6, d = i & 63;           // w2 is (H=16, D=64) row-major
        s_w2t[d * H + c] = w2[i];
    }
    if (tid < D) s_b1[tid] = b1[tid];
    if (tid < H) { s_b2[tid] = b2[tid]; s_g[tid] = ln_g[tid]; s_be[tid] = ln_b[tid]; }

    const int tile0 = blockIdx.x * BT;

    // ---- stage in: fully coalesced float4 loads -> padded LDS ----
    #pragma unroll
    for (int r = 0; r < 4; r++) {
        int idx = r * 256 + tid;              // float4 index within tile
        int w = idx * 4;                      // word index within tile
        int tt = w >> 4, e = w & 15;
        int gtok = tile0 + tt;
        if (gtok < ntok) {
            float4 v = *(const float4*)(x + (size_t)gtok * H + e);
            *(float4*)&s_x[tt * ROW + e] = v;
        }
    }
    __syncthreads();

    // ---- compute: one token per thread ----
    const int t = tile0 + tid;
    if (t < ntok) {
        float xs[H];
        #pragma unroll
        for (int r = 0; r < 4; r++) {
            float4 v = *(const float4*)&s_x[tid * ROW + r * 4];
            xs[r * 4 + 0] = v.x; xs[r * 4 + 1] = v.y;
            xs[r * 4 + 2] = v.z; xs[r * 4 + 3] = v.w;
        }

        // LayerNorm
        float sum = 0.f;
        #pragma unroll
        for (int k = 0; k < H; k++) sum += xs[k];
        const float mean = sum * (1.0f / H);
        float vs = 0.f;
        #pragma unroll
        for (int k = 0; k < H; k++) { float d = xs[k] - mean; vs = fmaf(d, d, vs); }
        const float inv = rsqrtf(vs * (1.0f / H) + 1e-5f);

        float y[H];
        #pragma unroll
        for (int k = 0; k < H; k++)
            y[k] = fmaf((xs[k] - mean) * inv, s_g[k], s_be[k]);

        // fused fc1 -> relu -> fc2 accumulate
        float o[H];
        #pragma unroll
        for (int c = 0; c < H; c++) o[c] = s_b2[c];

        #pragma unroll 8
        for (int d = 0; d < D; d++) {
            float a = s_b1[d];
            #pragma unroll
            for (int k = 0; k < H; k++) a = fmaf(y[k], s_w1[d * H + k], a);
            a = fmaxf(a, 0.f);
            #pragma unroll
            for (int c = 0; c < H; c++) o[c] = fmaf(a, s_w2t[d * H + c], o[c]);
        }

        // residual, write back to own LDS slot (thread-private, no barrier needed)
        #pragma unroll
        for (int r = 0; r < 4; r++) {
            float4 v = make_float4(o[r*4+0] + xs[r*4+0], o[r*4+1] + xs[r*4+1],
                                   o[r*4+2] + xs[r*4+2], o[r*4+3] + xs[r*4+3]);
            *(float4*)&s_x[tid * ROW + r * 4] = v;
        }
    }
    __syncthreads();

    // ---- stage out: padded LDS -> fully coalesced float4 stores ----
    #pragma unroll
    for (int r = 0; r < 4; r++) {
        int idx = r * 256 + tid;
        int w = idx * 4;
        int tt = w >> 4, e = w & 15;
        int gtok = tile0 + tt;
        if (gtok < ntok) {
            float4 v = *(const float4*)&s_x[tt * ROW + e];
            *(float4*)(out + (size_t)gtok * H + e) = v;
        }
    }
}

extern "C" void kernel_launch(void* const* d_in, const int* in_sizes, int n_in,
                              void* d_out, int out_size, void* d_ws, size_t ws_size,
                              hipStream_t stream) {
    const float* x   = (const float*)d_in[0];
    const float* g   = (const float*)d_in[1];
    const float* be  = (const float*)d_in[2];
    const float* w1  = (const float*)d_in[3];
    const float* b1  = (const float*)d_in[4];
    const float* w2  = (const float*)d_in[5];
    const float* b2  = (const float*)d_in[6];
    float* out = (float*)d_out;
    const int ntok = in_sizes[0] / H;

    const int block = 256;
    const int grid = (ntok + BT - 1) / BT;
    ffn_kernel<<<grid, block, 0, stream>>>(x, g, be, w1, b1, w2, b2, out, ntok);
}

// Round 3
// 170.425 us; speedup vs baseline: 2.7225x; 1.1686x over previous
//
#include <hip/hip_runtime.h>

// FFN: out = x + fc2(relu(fc1(LN(x)))), x:(ntok,16) fp32
// R3: weights read via wave-uniform global loads -> compiler emits s_load into
// SGPRs (scalar pipe / K$), freeing the LDS pipe that bottlenecked R2
// (512 broadcast ds_read_b128 per wave-pass). fc2 walks d in chunks of 8 so
// w2 rows are read as contiguous 32B spans (s_load_dwordx8) -- no transpose.
// LDS holds only the coalescing token tile (ROW=20 padding, conflict-free).

constexpr int H  = 16;
constexpr int D  = 64;
constexpr int BT = 256;   // tokens per block
constexpr int ROW = 20;   // padded words per token in LDS
constexpr int DC = 8;     // d-chunk size (w2 span = 32B = s_load_dwordx8)

__global__ __launch_bounds__(256, 8) void ffn_kernel(
    const float* __restrict__ x,
    const float* __restrict__ ln_g,
    const float* __restrict__ ln_b,
    const float* __restrict__ w1,
    const float* __restrict__ b1,
    const float* __restrict__ w2,
    const float* __restrict__ b2,
    float* __restrict__ out,
    int ntok)
{
    __shared__ float s_x[BT * ROW];   // 20 KB: in-tile, then out-tile

    const int tid = threadIdx.x;
    const int tile0 = blockIdx.x * BT;
    const bool full = (tile0 + BT <= ntok);   // block-uniform

    // ---- stage in: coalesced float4 -> padded LDS ----
    #pragma unroll
    for (int r = 0; r < 4; r++) {
        int idx = r * 256 + tid;
        int w4 = idx * 4, tt = w4 >> 4, e = w4 & 15;
        if (full || tile0 + tt < ntok)
            *(float4*)&s_x[tt * ROW + e] =
                *(const float4*)(x + (size_t)(tile0 + tt) * H + e);
    }
    __syncthreads();

    if (full || tile0 + tid < ntok) {
        // x row from LDS
        float xs[H];
        #pragma unroll
        for (int r = 0; r < 4; r++) {
            float4 v = *(const float4*)&s_x[tid * ROW + r * 4];
            xs[r*4+0] = v.x; xs[r*4+1] = v.y; xs[r*4+2] = v.z; xs[r*4+3] = v.w;
        }

        // LayerNorm
        float sum = 0.f;
        #pragma unroll
        for (int k = 0; k < H; k++) sum += xs[k];
        const float mean = sum * (1.0f / H);
        float vs = 0.f;
        #pragma unroll
        for (int k = 0; k < H; k++) { float d = xs[k] - mean; vs = fmaf(d, d, vs); }
        const float inv = rsqrtf(vs * (1.0f / H) + 1e-5f);

        float y[H];
        #pragma unroll
        for (int k = 0; k < H; k++)
            y[k] = fmaf((xs[k] - mean) * inv, ln_g[k], ln_b[k]);  // s_load params

        float o[H];
        #pragma unroll
        for (int c = 0; c < H; c++) o[c] = b2[c];                 // s_load

        // fc1 -> relu -> fc2, d in chunks of DC; all weight reads uniform -> SGPR
        for (int dc = 0; dc < D / DC; dc++) {
            float h[DC];
            #pragma unroll
            for (int j = 0; j < DC; j++) {
                const int d = dc * DC + j;
                float a = b1[d];
                #pragma unroll
                for (int k = 0; k < H; k++)
                    a = fmaf(y[k], w1[d * H + k], a);             // v,s,v FMA
                h[j] = fmaxf(a, 0.f);
            }
            #pragma unroll
            for (int c = 0; c < H; c++) {
                #pragma unroll
                for (int j = 0; j < DC; j++)
                    o[c] = fmaf(h[j], w2[c * D + dc * DC + j], o[c]);
            }
        }

        // residual (re-read x from own LDS slot) + write back in place
        #pragma unroll
        for (int r = 0; r < 4; r++) {
            float4 v = *(const float4*)&s_x[tid * ROW + r * 4];
            float4 w = make_float4(o[r*4+0] + v.x, o[r*4+1] + v.y,
                                   o[r*4+2] + v.z, o[r*4+3] + v.w);
            *(float4*)&s_x[tid * ROW + r * 4] = w;
        }
    }
    __syncthreads();

    // ---- stage out: padded LDS -> coalesced float4 ----
    #pragma unroll
    for (int r = 0; r < 4; r++) {
        int idx = r * 256 + tid;
        int w4 = idx * 4, tt = w4 >> 4, e = w4 & 15;
        if (full || tile0 + tt < ntok)
            *(float4*)(out + (size_t)(tile0 + tt) * H + e) =
                *(const float4*)&s_x[tt * ROW + e];
    }
}

extern "C" void kernel_launch(void* const* d_in, const int* in_sizes, int n_in,
                              void* d_out, int out_size, void* d_ws, size_t ws_size,
                              hipStream_t stream) {
    const float* x   = (const float*)d_in[0];
    const float* g   = (const float*)d_in[1];
    const float* be  = (const float*)d_in[2];
    const float* w1  = (const float*)d_in[3];
    const float* b1  = (const float*)d_in[4];
    const float* w2  = (const float*)d_in[5];
    const float* b2  = (const float*)d_in[6];
    float* out = (float*)d_out;
    const int ntok = in_sizes[0] / H;

    const int grid = (ntok + BT - 1) / BT;
    ffn_kernel<<<grid, 256, 0, stream>>>(x, g, be, w1, b1, w2, b2, out, ntok);
}

// Round 4
// 150.436 us; speedup vs baseline: 3.0842x; 1.1329x over previous
//
#include <hip/hip_runtime.h>

// FFN: out = x + fc2(relu(fc1(LN(x)))), x:(ntok,16) fp32, ntok % 256 == 0.
// R4: bf16 MFMA, transposed GEMMs. fc1: H^T = W1·Y^T, fc2: Out^T = W2·H^T
// (M = weight rows -> w1/w2 A-fragments are block-constant registers, loaded
// once; biases enter as the MFMA C operand). Per wave: 64 tokens; LN one
// token/lane; y and h round-trip through wave-private LDS scratch (overlaid
// region; in-order per-wave DS ops make it barrier-free). Single
// __syncthreads for the cooperative weight staging. Global I/O = coalesced
// float4 tile path (R2) -> HBM traffic stays at the 33/67 MB ideal.

constexpr int H = 16;
constexpr int D = 64;
constexpr int BT = 256;          // tokens per block (64 per wave)
constexpr int XROW = 20;         // x tile row stride, dwords (padded)
constexpr int YROW = 20;         // y row stride, dwords (16 data + 16 zero + pad)
constexpr int HROW = 36;         // h row stride, dwords (32 data + pad)
constexpr int WSCR = 64 * HROW;  // per-wave scratch dwords (y overlaid, then h)

typedef __attribute__((ext_vector_type(8))) short  short8;
typedef __attribute__((ext_vector_type(4))) float  floatx4;
typedef __attribute__((ext_vector_type(4))) unsigned uintx4;
typedef __attribute__((ext_vector_type(2))) unsigned uintx2;

__device__ inline unsigned short f2bf(float f) {
    unsigned u = __float_as_uint(f);
    return (unsigned short)((u + 0x7fffu + ((u >> 16) & 1u)) >> 16);  // RNE
}
__device__ inline unsigned pkbf(float a, float b) {
    return (unsigned)f2bf(a) | ((unsigned)f2bf(b) << 16);
}

__global__ __launch_bounds__(256, 2) void ffn_kernel(
    const float* __restrict__ x,
    const float* __restrict__ ln_g,
    const float* __restrict__ ln_b,
    const float* __restrict__ w1,
    const float* __restrict__ b1,
    const float* __restrict__ w2,
    const float* __restrict__ b2,
    float* __restrict__ out,
    int ntok)
{
    __shared__ __align__(16) float    s_x[BT * XROW];     // 20 KB in/out tile
    __shared__ __align__(16) float    s_scr[4 * WSCR];    // 36 KB wave scratch
    __shared__ __align__(16) unsigned s_w1[D * 20];       // bf16 rows, 40 hw
    __shared__ __align__(16) unsigned s_w2[H * 36];       // bf16 rows, 72 hw
    __shared__ __align__(16) float    s_b1[D];
    __shared__ __align__(16) float    s_b2[H];

    const int tid = threadIdx.x;
    const int w = tid >> 6, l = tid & 63;
    const int li = l & 15, q = l >> 4;

    // ---- weight staging (cooperative, bf16 + zero-pad k=16..31 for fc1) ----
    unsigned short* w1h = (unsigned short*)s_w1;
    for (int i = tid; i < D * 32; i += 256) {
        int d = i >> 5, k = i & 31;
        w1h[d * 40 + k] = (k < H) ? f2bf(w1[d * H + k]) : (unsigned short)0;
    }
    unsigned short* w2h = (unsigned short*)s_w2;
    for (int i = tid; i < H * D; i += 256) {
        int c = i >> 6, d = i & 63;
        w2h[c * 72 + d] = f2bf(w2[i]);
    }
    if (tid < D) s_b1[tid] = b1[tid];
    if (tid < H) s_b2[tid] = b2[tid];

    // ---- x stage-in (wave-private, coalesced float4) ----
    const size_t gbase = (size_t)(blockIdx.x * BT + w * 64) * H;  // floats
    #pragma unroll
    for (int r = 0; r < 4; r++) {
        int fi = (r * 64 + l) * 4;                 // float idx in wave chunk
        int tt = fi >> 4, e = fi & 15;
        floatx4 v = *(const floatx4*)(x + gbase + fi);
        *(floatx4*)&s_x[(w * 64 + tt) * XROW + e] = v;
    }
    __syncthreads();   // weights visible to all waves

    // ---- LayerNorm, one token per lane; y -> scratch as padded bf16 row ----
    float xs[H];
    #pragma unroll
    for (int r = 0; r < 4; r++) {
        floatx4 v = *(const floatx4*)&s_x[(w * 64 + l) * XROW + r * 4];
        xs[r*4+0] = v.x; xs[r*4+1] = v.y; xs[r*4+2] = v.z; xs[r*4+3] = v.w;
    }
    float sum = 0.f;
    #pragma unroll
    for (int k = 0; k < H; k++) sum += xs[k];
    const float mean = sum * (1.0f / H);
    float vs = 0.f;
    #pragma unroll
    for (int k = 0; k < H; k++) { float d = xs[k] - mean; vs = fmaf(d, d, vs); }
    const float inv = rsqrtf(vs * (1.0f / H) + 1e-5f);

    float yv[H];
    #pragma unroll
    for (int k = 0; k < H; k++)
        yv[k] = fmaf((xs[k] - mean) * inv, ln_g[k], ln_b[k]);   // uniform s_load

    unsigned* yrow = (unsigned*)&s_scr[w * WSCR + l * YROW];
    {
        uintx4 p0 = { pkbf(yv[0],yv[1]),  pkbf(yv[2],yv[3]),
                      pkbf(yv[4],yv[5]),  pkbf(yv[6],yv[7]) };
        uintx4 p1 = { pkbf(yv[8],yv[9]),  pkbf(yv[10],yv[11]),
                      pkbf(yv[12],yv[13]),pkbf(yv[14],yv[15]) };
        uintx4 z  = { 0u, 0u, 0u, 0u };
        *(uintx4*)&yrow[0]  = p0;
        *(uintx4*)&yrow[4]  = p1;
        *(uintx4*)&yrow[8]  = z;      // k = 16..31 zeros (K=32 padding)
        *(uintx4*)&yrow[12] = z;
    }

    // ---- block-constant fragments: A = weights, C = biases ----
    short8 a1[4], a2[2];
    floatx4 c1[4];
    #pragma unroll
    for (int mt = 0; mt < 4; mt++) {
        a1[mt] = *(const short8*)&w1h[(16*mt + li) * 40 + q * 8];   // A[d][k]
        c1[mt] = *(const floatx4*)&s_b1[16*mt + 4*q];               // b1 rows
    }
    #pragma unroll
    for (int kt = 0; kt < 2; kt++)
        a2[kt] = *(const short8*)&w2h[li * 72 + kt * 32 + q * 8];   // A[c][d]
    floatx4 c2 = *(const floatx4*)&s_b2[4*q];

    // ---- y fragments: read ALL before fc1 output overwrites scratch ----
    const unsigned short* scrh = (const unsigned short*)&s_scr[w * WSCR];
    short8 by[4];
    #pragma unroll
    for (int nt = 0; nt < 4; nt++)
        by[nt] = *(const short8*)&scrh[(16*nt + li) * 40 + q * 8];  // B[k][tok]

    // ---- fc1: H^T = relu(W1·Y^T + b1), write h rows [token][d] as bf16 ----
    unsigned* scru = (unsigned*)&s_scr[w * WSCR];
    #pragma unroll
    for (int nt = 0; nt < 4; nt++) {
        const int t = 16*nt + li;
        #pragma unroll
        for (int mt = 0; mt < 4; mt++) {
            floatx4 h = __builtin_amdgcn_mfma_f32_16x16x32_bf16(
                            a1[mt], by[nt], c1[mt], 0, 0, 0);
            h[0] = fmaxf(h[0], 0.f); h[1] = fmaxf(h[1], 0.f);
            h[2] = fmaxf(h[2], 0.f); h[3] = fmaxf(h[3], 0.f);
            // reg r holds h[d = 16mt+4q+r][token t]
            uintx2 hv = { pkbf(h[0], h[1]), pkbf(h[2], h[3]) };
            *(uintx2*)&scru[t * HROW + 8*mt + 2*q] = hv;
        }
    }

    // ---- fc2: Out^T = W2·H^T + b2, then residual via x tile ----
    #pragma unroll
    for (int nt = 0; nt < 4; nt++) {
        const int t = 16*nt + li;
        short8 h0 = *(const short8*)&scrh[t * 72 +  0 + q * 8];
        short8 h1 = *(const short8*)&scrh[t * 72 + 32 + q * 8];
        floatx4 o = __builtin_amdgcn_mfma_f32_16x16x32_bf16(a2[0], h0, c2, 0, 0, 0);
        o = __builtin_amdgcn_mfma_f32_16x16x32_bf16(a2[1], h1, o, 0, 0, 0);
        // reg r holds out^T[c = 4q+r][token t]; add residual, store to x tile
        float* xr = &s_x[(w*64 + t) * XROW + 4*q];
        floatx4 xv = *(const floatx4*)xr;
        o += xv;
        *(floatx4*)xr = o;
    }

    // ---- stage-out (wave-private rows were all written by this wave) ----
    #pragma unroll
    for (int r = 0; r < 4; r++) {
        int fi = (r * 64 + l) * 4;
        int tt = fi >> 4, e = fi & 15;
        floatx4 v = *(const floatx4*)&s_x[(w * 64 + tt) * XROW + e];
        *(floatx4*)(out + gbase + fi) = v;
    }
}

extern "C" void kernel_launch(void* const* d_in, const int* in_sizes, int n_in,
                              void* d_out, int out_size, void* d_ws, size_t ws_size,
                              hipStream_t stream) {
    const float* x   = (const float*)d_in[0];
    const float* g   = (const float*)d_in[1];
    const float* be  = (const float*)d_in[2];
    const float* w1  = (const float*)d_in[3];
    const float* b1  = (const float*)d_in[4];
    const float* w2  = (const float*)d_in[5];
    const float* b2  = (const float*)d_in[6];
    float* out = (float*)d_out;
    const int ntok = in_sizes[0] / H;           // 1048576, divisible by BT

    const int grid = ntok / BT;
    ffn_kernel<<<grid, 256, 0, stream>>>(x, g, be, w1, b1, w2, b2, out, ntok);
}

// Round 5
// 133.162 us; speedup vs baseline: 3.4843x; 1.1297x over previous
//
#include <hip/hip_runtime.h>
#include <hip/hip_bf16.h>

// FFN: out = x + fc2(relu(fc1(LN(x)))), x:(ntok,16) fp32, ntok % 256 == 0.
// R5: all-register MFMA chain. fc1 C-layout output == fc2 B-operand layout
// via delta-permuted w2 columns (staging-time), so no h LDS round-trip.
// LN reads x from the tile directly in B-fragment layout (half-wave rows,
// shfl_xor(16) for stats); b1 folded into w1 k=16 column (B slot q2/j0 = 1.0).
// LDS = 20KB x-tile + 7.4KB weights -> 5 blocks/CU (was 2 at 64KB).

constexpr int H = 16;
constexpr int D = 64;
constexpr int BT = 256;    // tokens per block (64 per wave)
constexpr int XROW = 20;   // x tile row stride, dwords (padded)
constexpr int W1R = 40;    // w1 row stride, ushorts (32 data + 8 pad)
constexpr int W2R = 72;    // w2 row stride, ushorts (64 data + 8 pad)

typedef __attribute__((ext_vector_type(8))) short  short8;
typedef __attribute__((ext_vector_type(4))) float  floatx4;
typedef __attribute__((ext_vector_type(4))) unsigned uintx4;

__device__ inline unsigned short f2bf(float f) {
    __hip_bfloat16 h = __float2bfloat16(f);        // RNE
    unsigned short u; __builtin_memcpy(&u, &h, 2); return u;
}
__device__ inline unsigned pk2(float a, float b) { // low = a, high = b
    __hip_bfloat162 h = __float22bfloat162_rn(make_float2(a, b));
    unsigned u; __builtin_memcpy(&u, &h, 4); return u;
}
__device__ inline floatx4 relu4(floatx4 v) {
    v.x = fmaxf(v.x, 0.f); v.y = fmaxf(v.y, 0.f);
    v.z = fmaxf(v.z, 0.f); v.w = fmaxf(v.w, 0.f);
    return v;
}

__global__ __launch_bounds__(256, 5) void ffn_kernel(
    const float* __restrict__ x,
    const float* __restrict__ ln_g,
    const float* __restrict__ ln_b,
    const float* __restrict__ w1,
    const float* __restrict__ b1,
    const float* __restrict__ w2,
    const float* __restrict__ b2,
    float* __restrict__ out,
    int ntok)
{
    __shared__ __align__(16) float          s_x[BT * XROW];   // 20 KB
    __shared__ __align__(16) unsigned short s_w1h[D * W1R];   // 5 KB
    __shared__ __align__(16) unsigned short s_w2h[H * W2R];   // 2.25 KB
    __shared__ __align__(16) float          s_b2[H];

    const int tid = threadIdx.x;
    const int w = tid >> 6, l = tid & 63;
    const int li = l & 15, q = l >> 4;

    // ---- prefetch x into registers (HBM latency hides behind staging) ----
    const size_t gbase = (size_t)(blockIdx.x * BT + w * 64) * H;
    floatx4 xin[4];
    #pragma unroll
    for (int r = 0; r < 4; r++)
        xin[r] = *(const floatx4*)(x + gbase + (r * 64 + l) * 4);

    // ---- stage w1 (b1 folded at k=16, zeros 17..31) ----
    for (int i = tid; i < D * 32; i += 256) {
        int d = i >> 5, k = i & 31;
        float v = (k < H) ? w1[d * H + k] : (k == H ? b1[d] : 0.f);
        s_w1h[d * W1R + k] = f2bf(v);
    }
    // ---- stage w2 with delta-permuted columns ----
    // delta(k) = 32*(k>>5) + 16*((k>>2)&1) + 4*((k>>3)&3) + (k&3)
    for (int i = tid; i < H * D; i += 256) {
        int c = i >> 6, k = i & 63;
        int dk = (k & 32) | (((k >> 2) & 1) << 4) | (((k >> 3) & 3) << 2) | (k & 3);
        s_w2h[c * W2R + k] = f2bf(w2[c * D + dk]);
    }
    if (tid < H) s_b2[tid] = b2[tid];

    // ---- write x tile ----
    #pragma unroll
    for (int r = 0; r < 4; r++) {
        int fi = (r * 64 + l) * 4, tt = fi >> 4, e = fi & 15;
        *(floatx4*)&s_x[(w * 64 + tt) * XROW + e] = xin[r];
    }
    __syncthreads();

    // ---- block-constant fragments ----
    short8 a1[4];
    #pragma unroll
    for (int mt = 0; mt < 4; mt++)
        a1[mt] = *(const short8*)&s_w1h[(16 * mt + li) * W1R + q * 8];
    short8 a2[2];
    #pragma unroll
    for (int kt = 0; kt < 2; kt++)
        a2[kt] = *(const short8*)&s_w2h[li * W2R + kt * 32 + q * 8];
    floatx4 c2 = *(const floatx4*)&s_b2[4 * q];

    const int k0 = (q & 1) * 8;            // x-element base this lane covers
    floatx4 ga = *(const floatx4*)(ln_g + k0);
    floatx4 gb = *(const floatx4*)(ln_g + k0 + 4);
    floatx4 ea = *(const floatx4*)(ln_b + k0);
    floatx4 eb = *(const floatx4*)(ln_b + k0 + 4);

    // ---- 4 n-tiles of 16 tokens each ----
    #pragma unroll
    for (int nt = 0; nt < 4; nt++) {
        float* xr = &s_x[(w * 64 + nt * 16 + li) * XROW];
        floatx4 xa = *(const floatx4*)(xr + k0);
        floatx4 xb = *(const floatx4*)(xr + k0 + 4);

        // LN stats: this lane has 8 of the 16 elements; partner is lane^16
        float ps = (xa.x + xa.y) + (xa.z + xa.w) + (xb.x + xb.y) + (xb.z + xb.w);
        float pq = 0.f;
        pq = fmaf(xa.x, xa.x, pq); pq = fmaf(xa.y, xa.y, pq);
        pq = fmaf(xa.z, xa.z, pq); pq = fmaf(xa.w, xa.w, pq);
        pq = fmaf(xb.x, xb.x, pq); pq = fmaf(xb.y, xb.y, pq);
        pq = fmaf(xb.z, xb.z, pq); pq = fmaf(xb.w, xb.w, pq);
        ps += __shfl_xor(ps, 16);
        pq += __shfl_xor(pq, 16);
        const float mean = ps * (1.0f / H);
        const float var  = fmaf(-mean, mean, pq * (1.0f / H));
        const float inv  = rsqrtf(var + 1e-5f);
        const float sa = inv, sb = -mean * inv;

        // y = ((x - mean)*inv)*g + b  for this lane's 8 elements
        float y0 = fmaf(fmaf(xa.x, sa, sb), ga.x, ea.x);
        float y1 = fmaf(fmaf(xa.y, sa, sb), ga.y, ea.y);
        float y2 = fmaf(fmaf(xa.z, sa, sb), ga.z, ea.z);
        float y3 = fmaf(fmaf(xa.w, sa, sb), ga.w, ea.w);
        float y4 = fmaf(fmaf(xb.x, sa, sb), gb.x, eb.x);
        float y5 = fmaf(fmaf(xb.y, sa, sb), gb.y, eb.y);
        float y6 = fmaf(fmaf(xb.z, sa, sb), gb.z, eb.z);
        float y7 = fmaf(fmaf(xb.w, sa, sb), gb.w, eb.w);

        unsigned p0 = pk2(y0, y1), p1 = pk2(y2, y3),
                 p2 = pk2(y4, y5), p3 = pk2(y6, y7);
        // q>=2 lanes: k=16 slot carries 1.0 (multiplies folded b1), rest 0
        if (q >= 2) { p0 = (q == 2) ? 0x3F80u : 0u; p1 = 0u; p2 = 0u; p3 = 0u; }
        uintx4 byu = { p0, p1, p2, p3 };
        short8 by; __builtin_memcpy(&by, &byu, 16);

        // fc1: 4 m-tiles, C = 0 (b1 folded into K)
        const floatx4 z = { 0.f, 0.f, 0.f, 0.f };
        floatx4 h0 = relu4(__builtin_amdgcn_mfma_f32_16x16x32_bf16(a1[0], by, z, 0, 0, 0));
        floatx4 h1 = relu4(__builtin_amdgcn_mfma_f32_16x16x32_bf16(a1[1], by, z, 0, 0, 0));
        floatx4 h2 = relu4(__builtin_amdgcn_mfma_f32_16x16x32_bf16(a1[2], by, z, 0, 0, 0));
        floatx4 h3 = relu4(__builtin_amdgcn_mfma_f32_16x16x32_bf16(a1[3], by, z, 0, 0, 0));

        // fc2 B operands: direct register repack of fc1 C output
        uintx4 bh0u = { pk2(h0.x, h0.y), pk2(h0.z, h0.w),
                        pk2(h1.x, h1.y), pk2(h1.z, h1.w) };
        uintx4 bh1u = { pk2(h2.x, h2.y), pk2(h2.z, h2.w),
                        pk2(h3.x, h3.y), pk2(h3.z, h3.w) };
        short8 bh0, bh1;
        __builtin_memcpy(&bh0, &bh0u, 16);
        __builtin_memcpy(&bh1, &bh1u, 16);

        floatx4 o = __builtin_amdgcn_mfma_f32_16x16x32_bf16(a2[0], bh0, c2, 0, 0, 0);
        o = __builtin_amdgcn_mfma_f32_16x16x32_bf16(a2[1], bh1, o, 0, 0, 0);

        // residual + write back to tile (wave-private row, DS in-order)
        floatx4 xres = *(const floatx4*)(xr + 4 * q);
        o += xres;
        *(floatx4*)(xr + 4 * q) = o;
    }

    // ---- stage out (rows written by this wave only) ----
    #pragma unroll
    for (int r = 0; r < 4; r++) {
        int fi = (r * 64 + l) * 4, tt = fi >> 4, e = fi & 15;
        *(floatx4*)(out + gbase + fi) = *(const floatx4*)&s_x[(w * 64 + tt) * XROW + e];
    }
}

extern "C" void kernel_launch(void* const* d_in, const int* in_sizes, int n_in,
                              void* d_out, int out_size, void* d_ws, size_t ws_size,
                              hipStream_t stream) {
    const float* x   = (const float*)d_in[0];
    const float* g   = (const float*)d_in[1];
    const float* be  = (const float*)d_in[2];
    const float* w1  = (const float*)d_in[3];
    const float* b1  = (const float*)d_in[4];
    const float* w2  = (const float*)d_in[5];
    const float* b2  = (const float*)d_in[6];
    float* out = (float*)d_out;
    const int ntok = in_sizes[0] / H;      // 1048576, divisible by BT

    const int grid = ntok / BT;
    ffn_kernel<<<grid, 256, 0, stream>>>(x, g, be, w1, b1, w2, b2, out, ntok);
}